// Round 2
// baseline (477.535 us; speedup 1.0000x reference)
//
#include <hip/hip_runtime.h>

// Problem constants (from setup_inputs): B=16, C_img=3, H=448, W=1024.
#define BB 16
#define HH 448
#define WW 1024
constexpr int HW    = HH * WW;            // 458752
constexpr int NBLK  = BB * HH;            // 7168 blocks, one per (b, row)
constexpr int NTHR  = 256;                // 256 thr x 4 px = one full row
constexpr long long TOTAL = (long long)BB * HW;

// Block = one image row: thread t owns pixels [4t, 4t+3].
// R1 lesson: this kernel is latency-bound -> TLP is king. 7168 blocks keeps
// 8 blocks/CU co-resident with 3.5 rounds of backfill (vs R1's 1792 blocks =
// single round, 39% occupancy). Down-row flow is re-loaded (2x redundancy,
// cache-absorbed) but as 6 coalesced float4 loads, not 24 scalars.

__global__ __launch_bounds__(NTHR) void elbo_main(
    const float* __restrict__ mean, const float* __restrict__ lvar,
    const float* __restrict__ img1, const float* __restrict__ img2,
    const float* __restrict__ target, const float* __restrict__ eps,
    float2* __restrict__ partials)
{
    // XCD-chunked bijective swizzle (NBLK % 8 == 0): each XCD gets 896
    // consecutive rows (= 2 whole images) -> img2 gather rows and the 2x
    // redundant down-row flow reads stay hot in its private L2.
    constexpr int NXCD = 8, CPX = NBLK / NXCD;
    const int wg = (blockIdx.x % NXCD) * CPX + blockIdx.x / NXCD;

    const int b = wg / HH;
    const int y = wg - b * HH;
    const int t = threadIdx.x;
    const int x = t << 2;                   // base x of this thread's float4

    const int o     = b * 2 * HW + y * WW + x;   // flow ch-0 offset at (y,x)
    const int ibase = b * 3 * HW;                // img ch-0 base

    float se = 0.f;   // elbo partial (data + smooth - 0.5*sum(logvar))
    float sp = 0.f;   // epe partial

    // ---- self flow row (float4, fully coalesced) + fused EPE/logvar ----
    const float4 m0 = *(const float4*)(mean + o);
    const float4 m1 = *(const float4*)(mean + o + HW);
    const float4 l0 = *(const float4*)(lvar + o);
    const float4 l1 = *(const float4*)(lvar + o + HW);
    const float4 e0 = *(const float4*)(eps  + o);
    const float4 e1 = *(const float4*)(eps  + o + HW);

    float u[4], v[4];
    u[0] = m0.x + __expf(0.5f * l0.x) * e0.x;
    u[1] = m0.y + __expf(0.5f * l0.y) * e0.y;
    u[2] = m0.z + __expf(0.5f * l0.z) * e0.z;
    u[3] = m0.w + __expf(0.5f * l0.w) * e0.w;
    v[0] = m1.x + __expf(0.5f * l1.x) * e1.x;
    v[1] = m1.y + __expf(0.5f * l1.y) * e1.y;
    v[2] = m1.z + __expf(0.5f * l1.z) * e1.z;
    v[3] = m1.w + __expf(0.5f * l1.w) * e1.w;

    {
        const float4 t0 = *(const float4*)(target + o);
        const float4 t1 = *(const float4*)(target + o + HW);
        float du, dv;
        du = m0.x - t0.x; dv = m1.x - t1.x; sp += sqrtf(du*du + dv*dv);
        du = m0.y - t0.y; dv = m1.y - t1.y; sp += sqrtf(du*du + dv*dv);
        du = m0.z - t0.z; dv = m1.z - t1.z; sp += sqrtf(du*du + dv*dv);
        du = m0.w - t0.w; dv = m1.w - t1.w; sp += sqrtf(du*du + dv*dv);
        se -= 0.5f * (l0.x + l0.y + l0.z + l0.w +
                      l1.x + l1.y + l1.z + l1.w);
    }

    // ---- down-row flow (float4; 2x redundant across blocks, L2-absorbed) ----
    const bool have_dn = (y + 1) < HH;
    float un[4] = {0, 0, 0, 0}, vn[4] = {0, 0, 0, 0};
    if (have_dn) {
        const int od = o + WW;
        const float4 dm0 = *(const float4*)(mean + od);
        const float4 dm1 = *(const float4*)(mean + od + HW);
        const float4 dl0 = *(const float4*)(lvar + od);
        const float4 dl1 = *(const float4*)(lvar + od + HW);
        const float4 de0 = *(const float4*)(eps  + od);
        const float4 de1 = *(const float4*)(eps  + od + HW);
        un[0] = dm0.x + __expf(0.5f * dl0.x) * de0.x;
        un[1] = dm0.y + __expf(0.5f * dl0.y) * de0.y;
        un[2] = dm0.z + __expf(0.5f * dl0.z) * de0.z;
        un[3] = dm0.w + __expf(0.5f * dl0.w) * de0.w;
        vn[0] = dm1.x + __expf(0.5f * dl1.x) * de1.x;
        vn[1] = dm1.y + __expf(0.5f * dl1.y) * de1.y;
        vn[2] = dm1.z + __expf(0.5f * dl1.z) * de1.z;
        vn[3] = dm1.w + __expf(0.5f * dl1.w) * de1.w;
    }

    // ---- right-neighbor flow at x+4 = next lane's pixel 0 ----
    float uR = __shfl_down(u[0], 1);
    float vR = __shfl_down(v[0], 1);
    if (((t & 63) == 63) && (t != NTHR - 1)) {   // wave-boundary fallback
        const int o4 = o + 4;
        uR = mean[o4]      + __expf(0.5f * lvar[o4])      * eps[o4];
        vR = mean[o4 + HW] + __expf(0.5f * lvar[o4 + HW]) * eps[o4 + HW];
    }

    // ---- img1 (float4 x 3 channels) ----
    const int ro = y * WW + x;
    const float4 g0 = *(const float4*)(img1 + ibase + ro);
    const float4 g1 = *(const float4*)(img1 + ibase + HW + ro);
    const float4 g2 = *(const float4*)(img1 + ibase + 2 * HW + ro);
    const float i1c0[4] = {g0.x, g0.y, g0.z, g0.w};
    const float i1c1[4] = {g1.x, g1.y, g1.z, g1.w};
    const float i1c2[4] = {g2.x, g2.y, g2.z, g2.w};

    const float* __restrict__ p2 = img2 + ibase;

    #pragma unroll
    for (int i = 0; i < 4; ++i) {
        const float ui = u[i], vi = v[i];
        const int gx = x + i;

        // ---- smoothness ----
        float dx2 = 0.f, dy2 = 0.f;
        if (gx < WW - 1) {
            const float ur = (i < 3) ? u[i + 1] : uR;
            const float vr = (i < 3) ? v[i + 1] : vR;
            const float a = ur - ui, c = vr - vi;
            dx2 = a * a + c * c;
        }
        if (have_dn) {
            const float a = un[i] - ui, c = vn[i] - vi;
            dy2 = a * a + c * c;
        }
        se += sqrtf(dx2 + dy2 + 1e-5f);

        // ---- data term: bilinear warp of img2 (12 independent gathers) ----
        const float xs = (float)gx + ui;
        const float ys = (float)y  + vi;
        const float x0f = floorf(xs), y0f = floorf(ys);
        const float wx = xs - x0f,    wy = ys - y0f;
        int x0 = (int)x0f; x0 = min(max(x0, 0), WW - 1);
        const int x1 = min(x0 + 1, WW - 1);
        int yy0 = (int)y0f; yy0 = min(max(yy0, 0), HH - 1);
        const int yy1 = min(yy0 + 1, HH - 1);
        const int i00 = yy0 * WW + x0, i01 = yy0 * WW + x1;
        const int i10 = yy1 * WW + x0, i11 = yy1 * WW + x1;

        float A = 0.f;
        {
            const float v00 = p2[i00], v01 = p2[i01];
            const float v10 = p2[i10], v11 = p2[i11];
            const float top = v00 + wx * (v01 - v00);
            const float bot = v10 + wx * (v11 - v10);
            const float w   = top + wy * (bot - top);
            const float d   = i1c0[i] - w;
            A += d * d;
        }
        {
            const float v00 = p2[HW + i00], v01 = p2[HW + i01];
            const float v10 = p2[HW + i10], v11 = p2[HW + i11];
            const float top = v00 + wx * (v01 - v00);
            const float bot = v10 + wx * (v11 - v10);
            const float w   = top + wy * (bot - top);
            const float d   = i1c1[i] - w;
            A += d * d;
        }
        {
            const float v00 = p2[2*HW + i00], v01 = p2[2*HW + i01];
            const float v10 = p2[2*HW + i10], v11 = p2[2*HW + i11];
            const float top = v00 + wx * (v01 - v00);
            const float bot = v10 + wx * (v11 - v10);
            const float w   = top + wy * (bot - top);
            const float d   = i1c2[i] - w;
            A += d * d;
        }
        se += sqrtf(A + 1e-5f);
    }

    // ---- block reduction: wave shuffle then LDS across 4 waves ----
    #pragma unroll
    for (int off = 32; off > 0; off >>= 1) {
        se += __shfl_down(se, off);
        sp += __shfl_down(sp, off);
    }
    __shared__ float s_e[NTHR / 64], s_p[NTHR / 64];
    const int lane = threadIdx.x & 63;
    const int wid  = threadIdx.x >> 6;
    if (lane == 0) { s_e[wid] = se; s_p[wid] = sp; }
    __syncthreads();
    if (threadIdx.x == 0) {
        float te = 0.0f, tp = 0.0f;
        #pragma unroll
        for (int i = 0; i < NTHR / 64; ++i) { te += s_e[i]; tp += s_p[i]; }
        partials[blockIdx.x] = make_float2(te, tp);
    }
}

__global__ __launch_bounds__(256) void elbo_final(
    const float2* __restrict__ partials, float* __restrict__ out)
{
    double se = 0.0, sp = 0.0;
    for (int i = threadIdx.x; i < NBLK; i += 256) {
        const float2 v = partials[i];
        se += (double)v.x;
        sp += (double)v.y;
    }
    #pragma unroll
    for (int off = 32; off > 0; off >>= 1) {
        se += __shfl_down(se, off);
        sp += __shfl_down(sp, off);
    }
    __shared__ double s_e[4], s_p[4];
    const int lane = threadIdx.x & 63;
    const int wid  = threadIdx.x >> 6;
    if (lane == 0) { s_e[wid] = se; s_p[wid] = sp; }
    __syncthreads();
    if (threadIdx.x == 0) {
        double te = 0.0, tp = 0.0;
        #pragma unroll
        for (int i = 0; i < 4; ++i) { te += s_e[i]; tp += s_p[i]; }
        out[0] = (float)(te / (double)BB);
        out[1] = (float)(tp / (double)TOTAL);
    }
}

extern "C" void kernel_launch(void* const* d_in, const int* in_sizes, int n_in,
                              void* d_out, int out_size, void* d_ws, size_t ws_size,
                              hipStream_t stream) {
    const float* mean   = (const float*)d_in[0];
    const float* logvar = (const float*)d_in[1];
    const float* img1   = (const float*)d_in[2];
    const float* img2   = (const float*)d_in[3];
    const float* target = (const float*)d_in[4];
    const float* eps    = (const float*)d_in[5];
    float* out = (float*)d_out;
    float2* partials = (float2*)d_ws;   // NBLK * 8 bytes = 56 KiB

    elbo_main<<<NBLK, NTHR, 0, stream>>>(mean, logvar, img1, img2, target, eps, partials);
    elbo_final<<<1, 256, 0, stream>>>(partials, out);
}

// Round 3
// 404.506 us; speedup vs baseline: 1.1805x; 1.1805x over previous
//
#include <hip/hip_runtime.h>

// Problem constants (from setup_inputs): B=16, C_img=3, H=448, W=1024.
#define BB 16
#define HH 448
#define WW 1024
constexpr int HW    = HH * WW;            // 458752
constexpr int NBLK  = BB * HH;            // 7168 blocks, one per (b, row)
constexpr int NTHR  = 256;
constexpr long long TOTAL = (long long)BB * HW;

// R1/R2 lesson (A/B/A evidence): thread-owns-consecutive-pixels quadruples
// L1 transactions on the gathers (each line touched by 4 separate instrs).
// Mapping here: consecutive lanes <-> consecutive x. Thread t handles
// x = t, t+256, t+512, t+768 of its row -> every load instruction's 64
// lanes span 256B contiguous = minimal lines/instr (R0's pattern).
// New vs R0: depth-1 pipeline on flow loads, shuffle right-neighbor,
// batched gather issue, XCD swizzle.

struct FlowRaw {           // raw inputs for one chunk (loaded 1 chunk ahead)
    float m0, m1, l0, l1, e0, e1;        // self row
    float dm0, dm1, dl0, dl1, de0, de1;  // down row
    float t0, t1;                        // target
};

__global__ __launch_bounds__(NTHR) void elbo_main(
    const float* __restrict__ mean, const float* __restrict__ lvar,
    const float* __restrict__ img1, const float* __restrict__ img2,
    const float* __restrict__ target, const float* __restrict__ eps,
    float2* __restrict__ partials)
{
    // XCD-chunked bijective swizzle (7168 % 8 == 0): each XCD owns 896
    // consecutive rows (2 whole images) -> down-row 2x flow re-reads and
    // img2 gather rows stay hot in its private L2.
    constexpr int NXCD = 8, CPX = NBLK / NXCD;
    const int wg = (blockIdx.x % NXCD) * CPX + blockIdx.x / NXCD;

    const int b = wg / HH;
    const int y = wg - b * HH;
    const int t = threadIdx.x;

    const int fbase = b * 2 * HW + y * WW;   // flow ch-0 offset of row start
    const int ibase = b * 3 * HW;
    const bool have_dn = (y + 1) < HH;       // false only for row 447

    const float* __restrict__ p2c0 = img2 + ibase;
    const float* __restrict__ p2c1 = img2 + ibase + HW;
    const float* __restrict__ p2c2 = img2 + ibase + 2 * HW;

    float se = 0.f;   // elbo partial (data + smooth - 0.5*sum(logvar))
    float sp = 0.f;   // epe partial

    // Issue one chunk's raw loads (14 scalars, all wave-coalesced).
    auto load_raw = [&](int k, FlowRaw& r) {
        const int o = fbase + (k << 8) + t;
        r.m0 = mean[o];   r.m1 = mean[o + HW];
        r.l0 = lvar[o];   r.l1 = lvar[o + HW];
        r.e0 = eps[o];    r.e1 = eps[o + HW];
        r.t0 = target[o]; r.t1 = target[o + HW];
        if (have_dn) {   // y=447: o+WW+HW would leave the allocation; guard
            r.dm0 = mean[o + WW]; r.dm1 = mean[o + WW + HW];
            r.dl0 = lvar[o + WW]; r.dl1 = lvar[o + WW + HW];
            r.de0 = eps[o + WW];  r.de1 = eps[o + WW + HW];
        } else {
            r.dm0 = r.dm1 = r.dl0 = r.dl1 = r.de0 = r.de1 = 0.f;
        }
    };

    FlowRaw cur, nxt;
    load_raw(0, cur);

    #pragma unroll
    for (int k = 0; k < 4; ++k) {
        // ---- pipeline: chunk k+1 flow loads fly during chunk k's gathers ----
        if (k < 3) load_raw(k + 1, nxt);

        const int x = (k << 8) + t;
        const int o = fbase + x;

        const float u = cur.m0 + __expf(0.5f * cur.l0) * cur.e0;
        const float v = cur.m1 + __expf(0.5f * cur.l1) * cur.e1;
        float un = 0.f, vn = 0.f;
        if (have_dn) {
            un = cur.dm0 + __expf(0.5f * cur.dl0) * cur.de0;
            vn = cur.dm1 + __expf(0.5f * cur.dl1) * cur.de1;
        }

        // ---- fused EPE + logvar ----
        {
            const float du = cur.m0 - cur.t0, dv = cur.m1 - cur.t1;
            sp += sqrtf(du * du + dv * dv);
        }
        se -= 0.5f * (cur.l0 + cur.l1);

        // ---- right-neighbor flow: next lane's value ----
        float uR = __shfl_down(u, 1);
        float vR = __shfl_down(v, 1);
        if (((t & 63) == 63) && (x + 1 < WW)) {   // wave-boundary fallback
            const int o1 = o + 1;
            uR = mean[o1]      + __expf(0.5f * lvar[o1])      * eps[o1];
            vR = mean[o1 + HW] + __expf(0.5f * lvar[o1 + HW]) * eps[o1 + HW];
        }

        // ---- smoothness ----
        float dx2 = 0.f, dy2 = 0.f;
        if (x < WW - 1) { const float a = uR - u, c = vR - v; dx2 = a * a + c * c; }
        if (have_dn)    { const float a = un - u, c = vn - v; dy2 = a * a + c * c; }
        se += sqrtf(dx2 + dy2 + 1e-5f);

        // ---- bilinear warp: addresses, then ALL loads, then math ----
        const float xs = (float)x + u;
        const float ys = (float)y + v;
        const float x0f = floorf(xs), y0f = floorf(ys);
        const float wx = xs - x0f,    wy = ys - y0f;
        int x0 = (int)x0f; x0 = min(max(x0, 0), WW - 1);
        const int x1 = min(x0 + 1, WW - 1);
        int yy0 = (int)y0f; yy0 = min(max(yy0, 0), HH - 1);
        const int yy1 = min(yy0 + 1, HH - 1);
        const int i00 = yy0 * WW + x0, i01 = yy0 * WW + x1;
        const int i10 = yy1 * WW + x0, i11 = yy1 * WW + x1;

        const int ro = y * WW + x;
        const float i1a = img1[ibase + ro];
        const float i1b = img1[ibase + HW + ro];
        const float i1c = img1[ibase + 2 * HW + ro];

        const float a00 = p2c0[i00], a01 = p2c0[i01], a10 = p2c0[i10], a11 = p2c0[i11];
        const float b00 = p2c1[i00], b01 = p2c1[i01], b10 = p2c1[i10], b11 = p2c1[i11];
        const float c00 = p2c2[i00], c01 = p2c2[i01], c10 = p2c2[i10], c11 = p2c2[i11];

        float A = 0.f;
        {
            const float top = a00 + wx * (a01 - a00);
            const float bot = a10 + wx * (a11 - a10);
            const float w   = top + wy * (bot - top);
            const float d   = i1a - w;  A += d * d;
        }
        {
            const float top = b00 + wx * (b01 - b00);
            const float bot = b10 + wx * (b11 - b10);
            const float w   = top + wy * (bot - top);
            const float d   = i1b - w;  A += d * d;
        }
        {
            const float top = c00 + wx * (c01 - c00);
            const float bot = c10 + wx * (c11 - c10);
            const float w   = top + wy * (bot - top);
            const float d   = i1c - w;  A += d * d;
        }
        se += sqrtf(A + 1e-5f);

        if (k < 3) cur = nxt;
    }

    // ---- block reduction: wave shuffle then LDS across 4 waves ----
    #pragma unroll
    for (int off = 32; off > 0; off >>= 1) {
        se += __shfl_down(se, off);
        sp += __shfl_down(sp, off);
    }
    __shared__ float s_e[NTHR / 64], s_p[NTHR / 64];
    const int lane = threadIdx.x & 63;
    const int wid  = threadIdx.x >> 6;
    if (lane == 0) { s_e[wid] = se; s_p[wid] = sp; }
    __syncthreads();
    if (threadIdx.x == 0) {
        float te = 0.0f, tp = 0.0f;
        #pragma unroll
        for (int i = 0; i < NTHR / 64; ++i) { te += s_e[i]; tp += s_p[i]; }
        partials[blockIdx.x] = make_float2(te, tp);
    }
}

__global__ __launch_bounds__(256) void elbo_final(
    const float2* __restrict__ partials, float* __restrict__ out)
{
    double se = 0.0, sp = 0.0;
    for (int i = threadIdx.x; i < NBLK; i += 256) {
        const float2 v = partials[i];
        se += (double)v.x;
        sp += (double)v.y;
    }
    #pragma unroll
    for (int off = 32; off > 0; off >>= 1) {
        se += __shfl_down(se, off);
        sp += __shfl_down(sp, off);
    }
    __shared__ double s_e[4], s_p[4];
    const int lane = threadIdx.x & 63;
    const int wid  = threadIdx.x >> 6;
    if (lane == 0) { s_e[wid] = se; s_p[wid] = sp; }
    __syncthreads();
    if (threadIdx.x == 0) {
        double te = 0.0, tp = 0.0;
        #pragma unroll
        for (int i = 0; i < 4; ++i) { te += s_e[i]; tp += s_p[i]; }
        out[0] = (float)(te / (double)BB);
        out[1] = (float)(tp / (double)TOTAL);
    }
}

extern "C" void kernel_launch(void* const* d_in, const int* in_sizes, int n_in,
                              void* d_out, int out_size, void* d_ws, size_t ws_size,
                              hipStream_t stream) {
    const float* mean   = (const float*)d_in[0];
    const float* logvar = (const float*)d_in[1];
    const float* img1   = (const float*)d_in[2];
    const float* img2   = (const float*)d_in[3];
    const float* target = (const float*)d_in[4];
    const float* eps    = (const float*)d_in[5];
    float* out = (float*)d_out;
    float2* partials = (float2*)d_ws;   // NBLK * 8 bytes = 56 KiB

    elbo_main<<<NBLK, NTHR, 0, stream>>>(mean, logvar, img1, img2, target, eps, partials);
    elbo_final<<<1, 256, 0, stream>>>(partials, out);
}

// Round 4
// 392.249 us; speedup vs baseline: 1.2174x; 1.0312x over previous
//
#include <hip/hip_runtime.h>

// Problem constants (from setup_inputs): B=16, C_img=3, H=448, W=1024.
#define BB 16
#define HH 448
#define WW 1024
constexpr int HW    = HH * WW;            // 458752
constexpr int NBLK  = BB * HH;            // 7168 blocks, one per (b, row)
constexpr int NTHR  = 256;
constexpr long long TOTAL = (long long)BB * HW;

// Evidence through R3: time is invariant to occupancy (32-84%), instruction
// count, and HBM bytes; only the lane<->address mapping matters. Theory:
// memory-request throughput / in-flight-capacity bound. This version batches
// ALL raw loads (56 flow/target + 12 img1) up front and ALL 48 gathers
// together -> ~4x outstanding requests per wave. Lane<->x mapping kept
// (R2 lesson: consecutive lanes must own consecutive x).

__global__ __launch_bounds__(NTHR) void elbo_main(
    const float* __restrict__ mean, const float* __restrict__ lvar,
    const float* __restrict__ img1, const float* __restrict__ img2,
    const float* __restrict__ target, const float* __restrict__ eps,
    float2* __restrict__ partials)
{
    // XCD-chunked bijective swizzle (7168 % 8 == 0).
    constexpr int NXCD = 8, CPX = NBLK / NXCD;
    const int wg = (blockIdx.x % NXCD) * CPX + blockIdx.x / NXCD;

    const int b = wg / HH;
    const int y = wg - b * HH;
    const int t = threadIdx.x;

    const int fbase = b * 2 * HW + y * WW;   // flow ch-0 offset of row start
    const int ibase = b * 3 * HW;
    const bool have_dn = (y + 1) < HH;       // false only for row 447

    const float* __restrict__ p2c0 = img2 + ibase;
    const float* __restrict__ p2c1 = img2 + ibase + HW;
    const float* __restrict__ p2c2 = img2 + ibase + 2 * HW;

    float se = 0.f;   // elbo partial (data + smooth - 0.5*sum(logvar))
    float sp = 0.f;   // epe partial

    // ---- phase 1: issue ALL raw loads (fully coalesced) ----
    float m0[4], m1[4], l0[4], l1[4], e0[4], e1[4], t0[4], t1[4];
    float dm0[4], dm1[4], dl0[4], dl1[4], de0[4], de1[4];
    float i1a[4], i1b[4], i1c[4];
    #pragma unroll
    for (int k = 0; k < 4; ++k) {
        const int o = fbase + (k << 8) + t;
        m0[k] = mean[o];   m1[k] = mean[o + HW];
        l0[k] = lvar[o];   l1[k] = lvar[o + HW];
        e0[k] = eps[o];    e1[k] = eps[o + HW];
        t0[k] = target[o]; t1[k] = target[o + HW];
    }
    if (have_dn) {
        #pragma unroll
        for (int k = 0; k < 4; ++k) {
            const int o = fbase + WW + (k << 8) + t;
            dm0[k] = mean[o]; dm1[k] = mean[o + HW];
            dl0[k] = lvar[o]; dl1[k] = lvar[o + HW];
            de0[k] = eps[o];  de1[k] = eps[o + HW];
        }
    }
    #pragma unroll
    for (int k = 0; k < 4; ++k) {
        const int ro = y * WW + (k << 8) + t;
        i1a[k] = img1[ibase + ro];
        i1b[k] = img1[ibase + HW + ro];
        i1c[k] = img1[ibase + 2 * HW + ro];
    }

    // ---- phase 2: flows, EPE, logvar, smoothness ----
    float u[4], v[4];
    #pragma unroll
    for (int k = 0; k < 4; ++k) {
        u[k] = m0[k] + __expf(0.5f * l0[k]) * e0[k];
        v[k] = m1[k] + __expf(0.5f * l1[k]) * e1[k];
        const float du = m0[k] - t0[k], dv = m1[k] - t1[k];
        sp += sqrtf(du * du + dv * dv);
        se -= 0.5f * (l0[k] + l1[k]);
    }
    #pragma unroll
    for (int k = 0; k < 4; ++k) {
        const int x = (k << 8) + t;
        float uR = __shfl_down(u[k], 1);
        float vR = __shfl_down(v[k], 1);
        if (((t & 63) == 63) && (x + 1 < WW)) {      // wave-boundary fallback
            const int o1 = fbase + x + 1;
            uR = mean[o1]      + __expf(0.5f * lvar[o1])      * eps[o1];
            vR = mean[o1 + HW] + __expf(0.5f * lvar[o1 + HW]) * eps[o1 + HW];
        }
        float dx2 = 0.f, dy2 = 0.f;
        if (x < WW - 1) { const float a = uR - u[k], c = vR - v[k]; dx2 = a * a + c * c; }
        if (have_dn) {
            const float un = dm0[k] + __expf(0.5f * dl0[k]) * de0[k];
            const float vn = dm1[k] + __expf(0.5f * dl1[k]) * de1[k];
            const float a = un - u[k], c = vn - v[k]; dy2 = a * a + c * c;
        }
        se += sqrtf(dx2 + dy2 + 1e-5f);
    }

    // ---- phase 3: issue ALL 48 gathers (12 per chunk, independent) ----
    float g[4][12], wxv[4], wyv[4];
    #pragma unroll
    for (int k = 0; k < 4; ++k) {
        const int x = (k << 8) + t;
        const float xs = (float)x + u[k];
        const float ys = (float)y + v[k];
        const float x0f = floorf(xs), y0f = floorf(ys);
        wxv[k] = xs - x0f; wyv[k] = ys - y0f;
        int x0 = (int)x0f; x0 = min(max(x0, 0), WW - 1);
        const int x1 = min(x0 + 1, WW - 1);
        int yy0 = (int)y0f; yy0 = min(max(yy0, 0), HH - 1);
        const int yy1 = min(yy0 + 1, HH - 1);
        const int i00 = yy0 * WW + x0, i01 = yy0 * WW + x1;
        const int i10 = yy1 * WW + x0, i11 = yy1 * WW + x1;
        g[k][0] = p2c0[i00]; g[k][1]  = p2c0[i01]; g[k][2]  = p2c0[i10]; g[k][3]  = p2c0[i11];
        g[k][4] = p2c1[i00]; g[k][5]  = p2c1[i01]; g[k][6]  = p2c1[i10]; g[k][7]  = p2c1[i11];
        g[k][8] = p2c2[i00]; g[k][9]  = p2c2[i01]; g[k][10] = p2c2[i10]; g[k][11] = p2c2[i11];
    }

    // ---- phase 4: interpolate + accumulate ----
    #pragma unroll
    for (int k = 0; k < 4; ++k) {
        const float wx = wxv[k], wy = wyv[k];
        float A = 0.f;
        {
            const float top = g[k][0] + wx * (g[k][1] - g[k][0]);
            const float bot = g[k][2] + wx * (g[k][3] - g[k][2]);
            const float w   = top + wy * (bot - top);
            const float d   = i1a[k] - w;  A += d * d;
        }
        {
            const float top = g[k][4] + wx * (g[k][5] - g[k][4]);
            const float bot = g[k][6] + wx * (g[k][7] - g[k][6]);
            const float w   = top + wy * (bot - top);
            const float d   = i1b[k] - w;  A += d * d;
        }
        {
            const float top = g[k][8] + wx * (g[k][9] - g[k][8]);
            const float bot = g[k][10] + wx * (g[k][11] - g[k][10]);
            const float w   = top + wy * (bot - top);
            const float d   = i1c[k] - w;  A += d * d;
        }
        se += sqrtf(A + 1e-5f);
    }

    // ---- block reduction: wave shuffle then LDS across 4 waves ----
    #pragma unroll
    for (int off = 32; off > 0; off >>= 1) {
        se += __shfl_down(se, off);
        sp += __shfl_down(sp, off);
    }
    __shared__ float s_e[NTHR / 64], s_p[NTHR / 64];
    const int lane = threadIdx.x & 63;
    const int wid  = threadIdx.x >> 6;
    if (lane == 0) { s_e[wid] = se; s_p[wid] = sp; }
    __syncthreads();
    if (threadIdx.x == 0) {
        float te = 0.0f, tp = 0.0f;
        #pragma unroll
        for (int i = 0; i < NTHR / 64; ++i) { te += s_e[i]; tp += s_p[i]; }
        partials[blockIdx.x] = make_float2(te, tp);
    }
}

// Final reduction rebuilt for MLP: 16 waves on one CU, each thread issues its
// 7 independent loads up front (one latency exposure) instead of a 28-round
// strided loop on 4 waves. Suspected source of the constant ~225 us gap
// between dur_us and the main dispatch.
__global__ __launch_bounds__(1024) void elbo_final(
    const float2* __restrict__ partials, float* __restrict__ out)
{
    constexpr int PER = NBLK / 1024;     // 7
    float2 v[PER];
    #pragma unroll
    for (int j = 0; j < PER; ++j) v[j] = partials[threadIdx.x + j * 1024];

    double se = 0.0, sp = 0.0;
    #pragma unroll
    for (int j = 0; j < PER; ++j) { se += (double)v[j].x; sp += (double)v[j].y; }

    #pragma unroll
    for (int off = 32; off > 0; off >>= 1) {
        se += __shfl_down(se, off);
        sp += __shfl_down(sp, off);
    }
    __shared__ double s_e[16], s_p[16];
    const int lane = threadIdx.x & 63;
    const int wid  = threadIdx.x >> 6;
    if (lane == 0) { s_e[wid] = se; s_p[wid] = sp; }
    __syncthreads();
    if (threadIdx.x == 0) {
        double te = 0.0, tp = 0.0;
        #pragma unroll
        for (int i = 0; i < 16; ++i) { te += s_e[i]; tp += s_p[i]; }
        out[0] = (float)(te / (double)BB);
        out[1] = (float)(tp / (double)TOTAL);
    }
}

extern "C" void kernel_launch(void* const* d_in, const int* in_sizes, int n_in,
                              void* d_out, int out_size, void* d_ws, size_t ws_size,
                              hipStream_t stream) {
    const float* mean   = (const float*)d_in[0];
    const float* logvar = (const float*)d_in[1];
    const float* img1   = (const float*)d_in[2];
    const float* img2   = (const float*)d_in[3];
    const float* target = (const float*)d_in[4];
    const float* eps    = (const float*)d_in[5];
    float* out = (float*)d_out;
    float2* partials = (float2*)d_ws;   // NBLK * 8 bytes = 56 KiB

    elbo_main<<<NBLK, NTHR, 0, stream>>>(mean, logvar, img1, img2, target, eps, partials);
    elbo_final<<<1, 1024, 0, stream>>>(partials, out);
}